// Round 9
// baseline (410.828 us; speedup 1.0000x reference)
//
#include <hip/hip_runtime.h>
#include <math.h>

#define Bn 4096
#define Dn 64
#define Kn 256
#define DKn 16384
#define SLAB ((size_t)262144)   // per-k slab in xh: Bn*Dn

typedef __attribute__((ext_vector_type(8))) short bf16x8;
typedef __attribute__((ext_vector_type(4))) float f32x4;
typedef unsigned short u16;
typedef unsigned int u32;

__device__ __forceinline__ float bf2f(u16 u) {
  return __uint_as_float(((u32)u) << 16);
}
__device__ __forceinline__ u16 f2bf(float f) {  // RNE
  u32 x = __float_as_uint(f);
  u32 r = x + 0x7fffu + ((x >> 16) & 1u);
  return (u16)(r >> 16);
}

// ---- K1: x[B,D,K] fp32 -> xh[k][b][d] bf16; f32 LDS tile, stride 65 --------
__global__ __launch_bounds__(256) void k1_transpose(
    const float* __restrict__ x, u16* __restrict__ xh) {
  __shared__ float tf[64][65];
  const int b0 = blockIdx.x * 8;
  const int k0 = blockIdx.y * 64;
  const int t = threadIdx.x;
  const int kq = t & 15, dsub = t >> 4;
  const int dq = t & 7, kr = t >> 3;

  for (int bb = 0; bb < 8; ++bb) {
    const int b = b0 + bb;
#pragma unroll
    for (int i = 0; i < 4; ++i) {
      const int d = dsub + 16 * i;
      const float4 v = *(const float4*)&x[(size_t)b * DKn + (size_t)d * Kn + k0 + 4 * kq];
      tf[4 * kq + 0][d] = v.x;
      tf[4 * kq + 1][d] = v.y;
      tf[4 * kq + 2][d] = v.z;
      tf[4 * kq + 3][d] = v.w;
    }
    __syncthreads();
#pragma unroll
    for (int it = 0; it < 2; ++it) {
      const int k = kr + 32 * it;
      u32 pk[4];
#pragma unroll
      for (int j = 0; j < 4; ++j) {
        const float f0 = tf[k][8 * dq + 2 * j];
        const float f1 = tf[k][8 * dq + 2 * j + 1];
        pk[j] = (u32)f2bf(f0) | ((u32)f2bf(f1) << 16);
      }
      *(uint4*)&xh[(size_t)(k0 + k) * SLAB + (size_t)b * 64 + 8 * dq] =
          make_uint4(pk[0], pk[1], pk[2], pk[3]);
    }
    __syncthreads();
  }
}

// ---- K2: raw moments partials via MFMA + mean partial sums -----------------
__global__ __launch_bounds__(256) void k2_cov(
    const u16* __restrict__ xh, float* __restrict__ covp, float* __restrict__ Sp) {
  __shared__ __align__(16) u16 tile[64][136];
  __shared__ float sred[64][65];
  const int part = blockIdx.x;
  const int k = blockIdx.y;
  const int t = threadIdx.x;
  const int w = t >> 6, l = t & 63;
  const int r16 = l & 15, g = l >> 4;
  const u16* pk = xh + (size_t)k * SLAB;

  f32x4 hh[10];
#pragma unroll
  for (int p = 0; p < 10; ++p) hh[p] = (f32x4){0.f, 0.f, 0.f, 0.f};
  float dsums[16];
#pragma unroll
  for (int q = 0; q < 16; ++q) dsums[q] = 0.f;

  for (int sub = 0; sub < 8; ++sub) {
    const int bbase = part * 1024 + sub * 128;
    __syncthreads();
#pragma unroll
    for (int iter = 0; iter < 2; ++iter) {
      const int dwc = w + 4 * iter;
      const uint4 v0 = *(const uint4*)&pk[(size_t)(bbase + 2 * l) * 64 + dwc * 8];
      const uint4 v1 = *(const uint4*)&pk[(size_t)(bbase + 2 * l + 1) * 64 + dwc * 8];
      const u16* p0 = (const u16*)&v0;
      const u16* p1 = (const u16*)&v1;
#pragma unroll
      for (int jj = 0; jj < 8; ++jj) {
        const u16 h0 = p0[jj], h1 = p1[jj];
        dsums[iter * 8 + jj] += bf2f(h0) + bf2f(h1);
        *(u32*)&tile[8 * dwc + jj][2 * l] = (u32)h0 | ((u32)h1 << 16);
      }
    }
    __syncthreads();
    bf16x8 fr[4];
#pragma unroll
    for (int m = 0; m < 4; ++m)
      fr[m] = *(const bf16x8*)&tile[16 * m + r16][32 * w + 8 * g];
#pragma unroll
    for (int m = 0; m < 4; ++m)
#pragma unroll
      for (int n = m; n < 4; ++n) {
        const int p = (m * (7 - m)) / 2 + n;
        hh[p] = __builtin_amdgcn_mfma_f32_16x16x32_bf16(fr[m], fr[n], hh[p], 0, 0, 0);
      }
  }
  float* cp = covp + ((size_t)k * 16 + part * 4 + w) * 2560;
#pragma unroll
  for (int p = 0; p < 10; ++p)
#pragma unroll
    for (int r = 0; r < 4; ++r)
      cp[p * 256 + (g * 4 + r) * 16 + r16] = hh[p][r];
#pragma unroll
  for (int iter = 0; iter < 2; ++iter)
#pragma unroll
    for (int jj = 0; jj < 8; ++jj)
      sred[8 * (w + 4 * iter) + jj][l] = dsums[iter * 8 + jj];
  __syncthreads();
  if (t < 64) {
    float s = 0.f;
#pragma unroll
    for (int q = 0; q < 64; ++q) s += sred[t][q];
    Sp[((size_t)k * 4 + part) * 64 + t] = s;
  }
}

// ---- K3: reduce -> cov -> Cholesky -> Linv (bf16 row-major) + v = Linv*mu --
__global__ __launch_bounds__(256) void k3_chol(
    const float* __restrict__ covp, const float* __restrict__ Sp,
    u16* __restrict__ wt, u16* __restrict__ vout) {
  __shared__ float a[64][65];
  __shared__ float mus[64];
  __shared__ float colv[64];
  __shared__ float diag;
  const int k = blockIdx.x;
  const int tid = threadIdx.x;
  if (tid < 64) {
    float s = 0.f;
#pragma unroll
    for (int q = 0; q < 4; ++q) s += Sp[((size_t)k * 4 + q) * 64 + tid];
    mus[tid] = s * (1.f / 4096.f);
  }
  __syncthreads();
  const float* cp = covp + (size_t)k * 16 * 2560;
  for (int idx = tid; idx < 4096; idx += 256) {
    const int i = idx >> 6, j = idx & 63;
    const int i16 = i >> 4, j16 = j >> 4, r = i & 15, c = j & 15;
    int p, off;
    if (i16 <= j16) { p = (i16 * (7 - i16)) / 2 + j16; off = r * 16 + c; }
    else            { p = (j16 * (7 - j16)) / 2 + i16; off = c * 16 + r; }
    float s = 0.f;
#pragma unroll
    for (int q = 0; q < 16; ++q) s += cp[q * 2560 + p * 256 + off];
    float cv = (s - 4096.f * mus[i] * mus[j]) * (1.f / 4095.f);
    if (i == j) cv += 1e-4f;
    a[i][j] = cv;
  }
  __syncthreads();
  for (int j = 0; j < 64; ++j) {
    if (tid == j) diag = sqrtf(a[j][j]);
    __syncthreads();
    const float ljj = diag;
    float lij = 0.f;
    if (tid == j) a[j][j] = ljj;
    if (tid < 64 && tid > j) {
      lij = a[tid][j] / ljj;
      a[tid][j] = lij;
      colv[tid] = lij;
    }
    __syncthreads();
    if (tid < 64 && tid > j)
      for (int e = j + 1; e <= tid; ++e) a[tid][e] -= lij * colv[e];
    __syncthreads();
  }
  float wv[64];
  if (tid < 64) {
#pragma unroll
    for (int i = 0; i < 64; ++i) {
      float s2 = (i == tid) ? 1.f : 0.f;
#pragma unroll
      for (int j = 0; j < i; ++j) s2 -= a[i][j] * wv[j];
      wv[i] = (i >= tid) ? s2 / a[i][i] : 0.f;
    }
  }
  __syncthreads();
  if (tid < 64) {
#pragma unroll
    for (int i = 0; i < 64; ++i) a[i][tid] = wv[i];  // a = Linv row-major
  }
  __syncthreads();
  if (tid < 64) {
    float v = 0.f;
#pragma unroll
    for (int e = 0; e < 64; ++e) v += a[tid][e] * mus[e];
    vout[(size_t)k * 64 + tid] = f2bf(v);
  }
#pragma unroll
  for (int it = 0; it < 8; ++it) {
    const int idx = it * 256 + tid;
    const int dd = idx >> 5, ep = idx & 31;
    const u32 pk2 = (u32)f2bf(a[dd][2 * ep]) | ((u32)f2bf(a[dd][2 * ep + 1]) << 16);
    *(u32*)&wt[(size_t)k * 4096 + 2 * idx] = pk2;
  }
}

// ---- K45: Z = Linv*x - v via MFMA; B-frags DIRECT from global (no staging,
//      no main-loop barriers); wt ring-4; k-major vector zls out -------------
// grid (256 b-tiles of 16, 8 k-chunks of 32), block 256 (4 waves = d-quarters)
__global__ __launch_bounds__(256) void k45_solve(
    const u16* __restrict__ xh, const u16* __restrict__ wt,
    const u16* __restrict__ vin, float* __restrict__ out) {
  __shared__ __align__(16) u32 zls[16 * 642 + 40];  // 41248 B, k-major retile
  __shared__ __align__(16) u16 vsh[32][72];         // [k][d]
  const int b0 = blockIdx.x * 16;
  const int kc0 = blockIdx.y * 32;
  const int t = threadIdx.x;
  const int w = t >> 6, l = t & 63;
  const int r16 = l & 15, g = l >> 4;
  const int d0 = 16 * w + 4 * g;

  *(uint4*)&vsh[t >> 3][8 * (t & 7)] = *(const uint4*)&vin[(size_t)kc0 * 64 + t * 8];
  __syncthreads();

  // B-frag global base: lane l reads xh[k][b0 + r16][8g .. 8g+8) (+32 for hi)
  const u16* xb = xh + (size_t)(b0 + r16) * 64 + 8 * g;

  // B ring, depth 2 (statically indexed via full unroll)
  bf16x8 blo[2], bhi[2];
  blo[0] = *(const bf16x8*)(xb + (size_t)(kc0 + 0) * SLAB);
  bhi[0] = *(const bf16x8*)(xb + (size_t)(kc0 + 0) * SLAB + 32);
  blo[1] = *(const bf16x8*)(xb + (size_t)(kc0 + 1) * SLAB);
  bhi[1] = *(const bf16x8*)(xb + (size_t)(kc0 + 1) * SLAB + 32);

  // A-frag (wt) ring, depth 4
  bf16x8 af0[4], af1[4];
#pragma unroll
  for (int p = 0; p < 4; ++p) {
    const u16* wk = wt + (size_t)(kc0 + p) * 4096 + (16 * w + r16) * 64 + 8 * g;
    af0[p] = *(const bf16x8*)(wk);
    af1[p] = *(const bf16x8*)(wk + 32);
  }

  u32 zr[64];  // packed bf16 of (Z - v): zr[2k]=(d0,d0+1), zr[2k+1]=(d0+2,d0+3)

#pragma unroll
  for (int kidx = 0; kidx < 32; ++kidx) {
    const int par = kidx & 1;
    const bf16x8 a0 = af0[kidx & 3];
    const bf16x8 a1 = af1[kidx & 3];
    if (kidx + 4 < 32) {  // refill wt ring
      const u16* wk = wt + (size_t)(kc0 + kidx + 4) * 4096 + (16 * w + r16) * 64 + 8 * g;
      af0[kidx & 3] = *(const bf16x8*)(wk);
      af1[kidx & 3] = *(const bf16x8*)(wk + 32);
    }
    f32x4 acc = (f32x4){0.f, 0.f, 0.f, 0.f};
    acc = __builtin_amdgcn_mfma_f32_16x16x32_bf16(a0, blo[par], acc, 0, 0, 0);
    acc = __builtin_amdgcn_mfma_f32_16x16x32_bf16(a1, bhi[par], acc, 0, 0, 0);
    if (kidx + 2 < 32) {  // refill B ring (slot just consumed)
      blo[par] = *(const bf16x8*)(xb + (size_t)(kc0 + kidx + 2) * SLAB);
      bhi[par] = *(const bf16x8*)(xb + (size_t)(kc0 + kidx + 2) * SLAB + 32);
    }
    // fp32 v-subtract (broadcast ds_read_b64), then HW packed bf16 convert
    const uint2 vv = *(const uint2*)&vsh[kidx][d0];
    const float s0 = acc[0] - __uint_as_float(vv.x << 16);
    const float s1 = acc[1] - __uint_as_float(vv.x & 0xffff0000u);
    const float s2 = acc[2] - __uint_as_float(vv.y << 16);
    const float s3 = acc[3] - __uint_as_float(vv.y & 0xffff0000u);
    u32 plo, phi;
    asm("v_cvt_pk_bf16_f32 %0, %1, %2" : "=v"(plo) : "v"(s0), "v"(s1));
    asm("v_cvt_pk_bf16_f32 %0, %1, %2" : "=v"(phi) : "v"(s2), "v"(s3));
    zr[2 * kidx] = plo;
    zr[2 * kidx + 1] = phi;
  }

  // out: two k-halves; register repack to k-major words, vector LDS retile
#pragma unroll
  for (int h = 0; h < 2; ++h) {
    u32 W[4][8];
#pragma unroll
    for (int r = 0; r < 4; ++r)
#pragma unroll
      for (int q = 0; q < 8; ++q) {
        const int k2 = 16 * h + 2 * q;
        const u32 za = zr[2 * k2 + (r >> 1)];
        const u32 zb2 = zr[2 * (k2 + 1) + (r >> 1)];
        W[r][q] = (r & 1) ? ((za >> 16) | (zb2 & 0xffff0000u))
                          : ((za & 0xffffu) | (zb2 << 16));
      }
#pragma unroll
    for (int r = 0; r < 4; ++r) {
      u32* cp = &zls[r16 * 642 + (d0 + r) * 10];
      *(uint2*)&cp[0] = make_uint2(W[r][0], W[r][1]);
      *(uint2*)&cp[2] = make_uint2(W[r][2], W[r][3]);
      *(uint2*)&cp[4] = make_uint2(W[r][4], W[r][5]);
      *(uint2*)&cp[6] = make_uint2(W[r][6], W[r][7]);
    }
    __syncthreads();
#pragma unroll
    for (int it = 0; it < 16; ++it) {
      const int c = w * 256 + it * 16 + (l >> 2);
      const int kc = l & 3;
      const int b = c >> 6, d = c & 63;
      const uint2 zw = *(const uint2*)&zls[b * 642 + d * 10 + 2 * kc];
      float4 ov;
      ov.x = __uint_as_float(zw.x << 16);
      ov.y = __uint_as_float(zw.x & 0xffff0000u);
      ov.z = __uint_as_float(zw.y << 16);
      ov.w = __uint_as_float(zw.y & 0xffff0000u);
      *(float4*)&out[(size_t)(b0 + b) * DKn + (size_t)d * Kn + kc0 + 16 * h + 4 * kc] = ov;
    }
    __syncthreads();
  }
}

extern "C" void kernel_launch(void* const* d_in, const int* in_sizes, int n_in,
                              void* d_out, int out_size, void* d_ws, size_t ws_size,
                              hipStream_t stream) {
  (void)in_sizes; (void)n_in; (void)out_size;
  const float* x = (const float*)d_in[0];
  float* out = (float*)d_out;
  char* ws = (char*)d_ws;
  const size_t XH_B = 134217728;   // u16 [256][4096][64]
  const size_t CP_B = 41943040;    // f32 [256][16][2560]
  const size_t SP_B = 262144;      // f32 [256][4][64]
  const size_t WT_B = 2097152;     // u16 [256][64][64]
  const size_t V_B  = 32768;       // u16 [256][64]
  if (ws_size < XH_B + CP_B + SP_B + WT_B + V_B) return;
  u16* xh = (u16*)ws;
  float* covp = (float*)(ws + XH_B);
  float* Sp = (float*)(ws + XH_B + CP_B);
  u16* wtb = (u16*)(ws + XH_B + CP_B + SP_B);
  u16* vb  = (u16*)(ws + XH_B + CP_B + SP_B + WT_B);

  k1_transpose<<<dim3(512, 4), 256, 0, stream>>>(x, xh);
  k2_cov<<<dim3(4, 256), 256, 0, stream>>>(xh, covp, Sp);
  k3_chol<<<dim3(256), 256, 0, stream>>>(covp, Sp, wtb, vb);
  k45_solve<<<dim3(256, 8), 256, 0, stream>>>(xh, wtb, vb, out);
}

// Round 10
// 361.648 us; speedup vs baseline: 1.1360x; 1.1360x over previous
//
#include <hip/hip_runtime.h>
#include <math.h>

#define Bn 4096
#define Dn 64
#define Kn 256
#define DKn 16384
#define SLAB ((size_t)262144)   // per-k slab in xh: Bn*Dn

typedef __attribute__((ext_vector_type(8))) short bf16x8;
typedef __attribute__((ext_vector_type(4))) float f32x4;
typedef unsigned short u16;
typedef unsigned int u32;

__device__ __forceinline__ float bf2f(u16 u) {
  return __uint_as_float(((u32)u) << 16);
}
__device__ __forceinline__ u16 f2bf(float f) {  // RNE
  u32 x = __float_as_uint(f);
  u32 r = x + 0x7fffu + ((x >> 16) & 1u);
  return (u16)(r >> 16);
}

// ---- K1: x[B,D,K] fp32 -> xh[k][b][d] bf16; f32 LDS tile, stride 65 --------
__global__ __launch_bounds__(256) void k1_transpose(
    const float* __restrict__ x, u16* __restrict__ xh) {
  __shared__ float tf[64][65];
  const int b0 = blockIdx.x * 8;
  const int k0 = blockIdx.y * 64;
  const int t = threadIdx.x;
  const int kq = t & 15, dsub = t >> 4;
  const int dq = t & 7, kr = t >> 3;

  for (int bb = 0; bb < 8; ++bb) {
    const int b = b0 + bb;
#pragma unroll
    for (int i = 0; i < 4; ++i) {
      const int d = dsub + 16 * i;
      const float4 v = *(const float4*)&x[(size_t)b * DKn + (size_t)d * Kn + k0 + 4 * kq];
      tf[4 * kq + 0][d] = v.x;
      tf[4 * kq + 1][d] = v.y;
      tf[4 * kq + 2][d] = v.z;
      tf[4 * kq + 3][d] = v.w;
    }
    __syncthreads();
#pragma unroll
    for (int it = 0; it < 2; ++it) {
      const int k = kr + 32 * it;
      u32 pk[4];
#pragma unroll
      for (int j = 0; j < 4; ++j) {
        const float f0 = tf[k][8 * dq + 2 * j];
        const float f1 = tf[k][8 * dq + 2 * j + 1];
        pk[j] = (u32)f2bf(f0) | ((u32)f2bf(f1) << 16);
      }
      *(uint4*)&xh[(size_t)(k0 + k) * SLAB + (size_t)b * 64 + 8 * dq] =
          make_uint4(pk[0], pk[1], pk[2], pk[3]);
    }
    __syncthreads();
  }
}

// ---- K2: raw moments via MFMA; COALESCED staging + swizzled LDS transpose ---
// grid (4 parts of 1024 b, 256 k), block 256 (4 waves; wave w = b-strip 32w)
__global__ __launch_bounds__(256) void k2_cov(
    const u16* __restrict__ xh, float* __restrict__ covp, float* __restrict__ Sp) {
  __shared__ __align__(16) u16 tile[64][136];  // [d][b], u32-col swizzled by 4*((d>>2)&7)
  __shared__ float sred[64][33];
  const int part = blockIdx.x;
  const int k = blockIdx.y;
  const int t = threadIdx.x;
  const int w = t >> 6, l = t & 63;
  const int r16 = l & 15, g = l >> 4;
  const int q = t >> 3, c = t & 7;  // q 0..31 (4-row group), c 0..7 (d-chunk)
  const u16* pk = xh + (size_t)k * SLAB;

  f32x4 hh[10];
#pragma unroll
  for (int p = 0; p < 10; ++p) hh[p] = (f32x4){0.f, 0.f, 0.f, 0.f};
  float dsums[8];
#pragma unroll
  for (int jj = 0; jj < 8; ++jj) dsums[jj] = 0.f;

  for (int sub = 0; sub < 8; ++sub) {
    const int bbase = part * 1024 + sub * 128;
    __syncthreads();
    // coalesced: thread reads 4 consecutive b-rows, one 16B d-chunk each.
    // per wave instr: 8 full 128B lines (contiguous), vs 64x16B scatter before.
    uint4 pv[4];
#pragma unroll
    for (int i = 0; i < 4; ++i)
      pv[i] = *(const uint4*)&pk[(size_t)(bbase + 4 * q + i) * 64 + c * 8];
    const u16* e0 = (const u16*)&pv[0];
    const u16* e1 = (const u16*)&pv[1];
    const u16* e2 = (const u16*)&pv[2];
    const u16* e3 = (const u16*)&pv[3];
#pragma unroll
    for (int jj = 0; jj < 8; ++jj) {
      const int d = 8 * c + jj;
      const int s4 = 4 * ((d >> 2) & 7);          // u32-col XOR swizzle
      const u16 v0 = e0[jj], v1 = e1[jj], v2 = e2[jj], v3 = e3[jj];
      dsums[jj] += (bf2f(v0) + bf2f(v1)) + (bf2f(v2) + bf2f(v3));
      const int col0 = (2 * q) ^ s4;              // even; col1 = col0+1
      uint2 st;
      st.x = (u32)v0 | ((u32)v1 << 16);           // b = 4q, 4q+1
      st.y = (u32)v2 | ((u32)v3 << 16);           // b = 4q+2, 4q+3
      *(uint2*)&tile[d][2 * col0] = st;           // 8B store, 8B-aligned
    }
    __syncthreads();
    bf16x8 fr[4];
#pragma unroll
    for (int m = 0; m < 4; ++m) {
      const int d = 16 * m + r16;
      const int s4 = 4 * ((d >> 2) & 7);
      const int colb = (16 * w + 4 * g) ^ s4;     // chunk-aligned (mult of 4)
      fr[m] = *(const bf16x8*)&tile[d][2 * colb];
    }
#pragma unroll
    for (int m = 0; m < 4; ++m)
#pragma unroll
      for (int n = m; n < 4; ++n) {
        const int p = (m * (7 - m)) / 2 + n;
        hh[p] = __builtin_amdgcn_mfma_f32_16x16x32_bf16(fr[m], fr[n], hh[p], 0, 0, 0);
      }
  }
  float* cp = covp + ((size_t)k * 16 + part * 4 + w) * 2560;
#pragma unroll
  for (int p = 0; p < 10; ++p)
#pragma unroll
    for (int r = 0; r < 4; ++r)
      cp[p * 256 + (g * 4 + r) * 16 + r16] = hh[p][r];
#pragma unroll
  for (int jj = 0; jj < 8; ++jj) sred[8 * c + jj][q] = dsums[jj];
  __syncthreads();
  if (t < 64) {
    float s = 0.f;
#pragma unroll
    for (int q2 = 0; q2 < 32; ++q2) s += sred[t][q2];
    Sp[((size_t)k * 4 + part) * 64 + t] = s;
  }
}

// ---- K3: reduce -> cov -> Cholesky -> Linv (bf16 row-major) + v = Linv*mu --
__global__ __launch_bounds__(256) void k3_chol(
    const float* __restrict__ covp, const float* __restrict__ Sp,
    u16* __restrict__ wt, u16* __restrict__ vout) {
  __shared__ float a[64][65];
  __shared__ float mus[64];
  __shared__ float colv[64];
  __shared__ float diag;
  const int k = blockIdx.x;
  const int tid = threadIdx.x;
  if (tid < 64) {
    float s = 0.f;
#pragma unroll
    for (int q = 0; q < 4; ++q) s += Sp[((size_t)k * 4 + q) * 64 + tid];
    mus[tid] = s * (1.f / 4096.f);
  }
  __syncthreads();
  const float* cp = covp + (size_t)k * 16 * 2560;
  for (int idx = tid; idx < 4096; idx += 256) {
    const int i = idx >> 6, j = idx & 63;
    const int i16 = i >> 4, j16 = j >> 4, r = i & 15, c = j & 15;
    int p, off;
    if (i16 <= j16) { p = (i16 * (7 - i16)) / 2 + j16; off = r * 16 + c; }
    else            { p = (j16 * (7 - j16)) / 2 + i16; off = c * 16 + r; }
    float s = 0.f;
#pragma unroll
    for (int q = 0; q < 16; ++q) s += cp[q * 2560 + p * 256 + off];
    float cv = (s - 4096.f * mus[i] * mus[j]) * (1.f / 4095.f);
    if (i == j) cv += 1e-4f;
    a[i][j] = cv;
  }
  __syncthreads();
  for (int j = 0; j < 64; ++j) {
    if (tid == j) diag = sqrtf(a[j][j]);
    __syncthreads();
    const float ljj = diag;
    float lij = 0.f;
    if (tid == j) a[j][j] = ljj;
    if (tid < 64 && tid > j) {
      lij = a[tid][j] / ljj;
      a[tid][j] = lij;
      colv[tid] = lij;
    }
    __syncthreads();
    if (tid < 64 && tid > j)
      for (int e = j + 1; e <= tid; ++e) a[tid][e] -= lij * colv[e];
    __syncthreads();
  }
  float wv[64];
  if (tid < 64) {
#pragma unroll
    for (int i = 0; i < 64; ++i) {
      float s2 = (i == tid) ? 1.f : 0.f;
#pragma unroll
      for (int j = 0; j < i; ++j) s2 -= a[i][j] * wv[j];
      wv[i] = (i >= tid) ? s2 / a[i][i] : 0.f;
    }
  }
  __syncthreads();
  if (tid < 64) {
#pragma unroll
    for (int i = 0; i < 64; ++i) a[i][tid] = wv[i];  // a = Linv row-major
  }
  __syncthreads();
  if (tid < 64) {
    float v = 0.f;
#pragma unroll
    for (int e = 0; e < 64; ++e) v += a[tid][e] * mus[e];
    vout[(size_t)k * 64 + tid] = f2bf(v);
  }
#pragma unroll
  for (int it = 0; it < 8; ++it) {
    const int idx = it * 256 + tid;
    const int dd = idx >> 5, ep = idx & 31;
    const u32 pk2 = (u32)f2bf(a[dd][2 * ep]) | ((u32)f2bf(a[dd][2 * ep + 1]) << 16);
    *(u32*)&wt[(size_t)k * 4096 + 2 * idx] = pk2;
  }
}

// ---- K45 (R8 version, reverted): LDS-staged B, cvt_pk, k-major zls out -----
// grid (256 b-tiles of 16, 8 k-chunks of 32), block 256 (4 waves = d-quarters)
union __align__(16) SMemU {
  u16 xstage[2][8][16][64];  // [buf][k][b][d], d-chunk XOR-swizzled by b&7 (32768 B)
  u32 zls[16 * 642 + 40];    // 41248 B
};

__global__ __launch_bounds__(256) void k45_solve(
    const u16* __restrict__ xh, const u16* __restrict__ wt,
    const u16* __restrict__ vin, float* __restrict__ out) {
  __shared__ SMemU sm;
  __shared__ __align__(16) u16 vsh[32][72];  // [k][d]
  const int b0 = blockIdx.x * 16;
  const int kc0 = blockIdx.y * 32;
  const int t = threadIdx.x;
  const int w = t >> 6, l = t & 63;
  const int r16 = l & 15, g = l >> 4;
  const int d0 = 16 * w + 4 * g;

  *(uint4*)&vsh[t >> 3][8 * (t & 7)] = *(const uint4*)&vin[(size_t)kc0 * 64 + t * 8];

  // prologue: load + stage round 0 (swizzled)
  uint4 sv[4];
#pragma unroll
  for (int i = 0; i < 4; ++i) {
    const int idx = i * 256 + t;
    const int kk = idx >> 7, b = (idx >> 3) & 15, dc = idx & 7;
    sv[i] = *(const uint4*)&xh[(size_t)(kc0 + kk) * SLAB + (size_t)(b0 + b) * 64 + dc * 8];
  }
#pragma unroll
  for (int i = 0; i < 4; ++i) {
    const int idx = i * 256 + t;
    const int kk = idx >> 7, b = (idx >> 3) & 15, dc = idx & 7;
    *(uint4*)&sm.xstage[0][kk][b][(dc ^ (b & 7)) * 8] = sv[i];
  }

  // A-frag ring prefetch, depth 4
  bf16x8 af0[4], af1[4];
#pragma unroll
  for (int p = 0; p < 4; ++p) {
    const u16* wk = wt + (size_t)(kc0 + p) * 4096 + (16 * w + r16) * 64 + 8 * g;
    af0[p] = *(const bf16x8*)(wk);
    af1[p] = *(const bf16x8*)(wk + 32);
  }
  __syncthreads();

  u32 zr[64];  // packed bf16 of (Z - v): zr[2k]=(d0,d0+1), zr[2k+1]=(d0+2,d0+3)

#pragma unroll
  for (int rnd = 0; rnd < 4; ++rnd) {
    if (rnd < 3) {
#pragma unroll
      for (int i = 0; i < 4; ++i) {
        const int idx = i * 256 + t;
        const int kk = idx >> 7, b = (idx >> 3) & 15, dc = idx & 7;
        sv[i] = *(const uint4*)&xh[(size_t)(kc0 + (rnd + 1) * 8 + kk) * SLAB +
                                   (size_t)(b0 + b) * 64 + dc * 8];
      }
    }
#pragma unroll
    for (int kk = 0; kk < 8; ++kk) {
      const int kidx = rnd * 8 + kk;
      const bf16x8 a0 = af0[kidx & 3];
      const bf16x8 a1 = af1[kidx & 3];
      if (kidx + 4 < 32) {
        const u16* wk = wt + (size_t)(kc0 + kidx + 4) * 4096 + (16 * w + r16) * 64 + 8 * g;
        af0[kidx & 3] = *(const bf16x8*)(wk);
        af1[kidx & 3] = *(const bf16x8*)(wk + 32);
      }
      const bf16x8 bf0 = *(const bf16x8*)&sm.xstage[rnd & 1][kk][r16][(g ^ (r16 & 7)) * 8];
      const bf16x8 bf1 = *(const bf16x8*)&sm.xstage[rnd & 1][kk][r16][((4 + g) ^ (r16 & 7)) * 8];
      f32x4 acc = (f32x4){0.f, 0.f, 0.f, 0.f};
      acc = __builtin_amdgcn_mfma_f32_16x16x32_bf16(a0, bf0, acc, 0, 0, 0);
      acc = __builtin_amdgcn_mfma_f32_16x16x32_bf16(a1, bf1, acc, 0, 0, 0);
      const uint2 vv = *(const uint2*)&vsh[kidx][d0];
      const float s0 = acc[0] - __uint_as_float(vv.x << 16);
      const float s1 = acc[1] - __uint_as_float(vv.x & 0xffff0000u);
      const float s2 = acc[2] - __uint_as_float(vv.y << 16);
      const float s3 = acc[3] - __uint_as_float(vv.y & 0xffff0000u);
      u32 plo, phi;
      asm("v_cvt_pk_bf16_f32 %0, %1, %2" : "=v"(plo) : "v"(s0), "v"(s1));
      asm("v_cvt_pk_bf16_f32 %0, %1, %2" : "=v"(phi) : "v"(s2), "v"(s3));
      zr[2 * kidx] = plo;
      zr[2 * kidx + 1] = phi;
    }
    if (rnd < 3) {
#pragma unroll
      for (int i = 0; i < 4; ++i) {
        const int idx = i * 256 + t;
        const int kk = idx >> 7, b = (idx >> 3) & 15, dc = idx & 7;
        *(uint4*)&sm.xstage[(rnd + 1) & 1][kk][b][(dc ^ (b & 7)) * 8] = sv[i];
      }
      __syncthreads();
    }
  }
  __syncthreads();  // all MFMA reads of xstage done before zls overlays it

  // out: two k-halves; register repack to k-major words, vector LDS retile
#pragma unroll
  for (int h = 0; h < 2; ++h) {
    u32 W[4][8];
#pragma unroll
    for (int r = 0; r < 4; ++r)
#pragma unroll
      for (int q2 = 0; q2 < 8; ++q2) {
        const int k2 = 16 * h + 2 * q2;
        const u32 za = zr[2 * k2 + (r >> 1)];
        const u32 zb2 = zr[2 * (k2 + 1) + (r >> 1)];
        W[r][q2] = (r & 1) ? ((za >> 16) | (zb2 & 0xffff0000u))
                           : ((za & 0xffffu) | (zb2 << 16));
      }
#pragma unroll
    for (int r = 0; r < 4; ++r) {
      u32* cp = &sm.zls[r16 * 642 + (d0 + r) * 10];
      *(uint2*)&cp[0] = make_uint2(W[r][0], W[r][1]);
      *(uint2*)&cp[2] = make_uint2(W[r][2], W[r][3]);
      *(uint2*)&cp[4] = make_uint2(W[r][4], W[r][5]);
      *(uint2*)&cp[6] = make_uint2(W[r][6], W[r][7]);
    }
    __syncthreads();
#pragma unroll
    for (int it = 0; it < 16; ++it) {
      const int c = w * 256 + it * 16 + (l >> 2);
      const int kc = l & 3;
      const int b = c >> 6, d = c & 63;
      const uint2 zw = *(const uint2*)&sm.zls[b * 642 + d * 10 + 2 * kc];
      float4 ov;
      ov.x = __uint_as_float(zw.x << 16);
      ov.y = __uint_as_float(zw.x & 0xffff0000u);
      ov.z = __uint_as_float(zw.y << 16);
      ov.w = __uint_as_float(zw.y & 0xffff0000u);
      *(float4*)&out[(size_t)(b0 + b) * DKn + (size_t)d * Kn + kc0 + 16 * h + 4 * kc] = ov;
    }
    __syncthreads();
  }
}

extern "C" void kernel_launch(void* const* d_in, const int* in_sizes, int n_in,
                              void* d_out, int out_size, void* d_ws, size_t ws_size,
                              hipStream_t stream) {
  (void)in_sizes; (void)n_in; (void)out_size;
  const float* x = (const float*)d_in[0];
  float* out = (float*)d_out;
  char* ws = (char*)d_ws;
  const size_t XH_B = 134217728;   // u16 [256][4096][64]
  const size_t CP_B = 41943040;    // f32 [256][16][2560]
  const size_t SP_B = 262144;      // f32 [256][4][64]
  const size_t WT_B = 2097152;     // u16 [256][64][64]
  const size_t V_B  = 32768;       // u16 [256][64]
  if (ws_size < XH_B + CP_B + SP_B + WT_B + V_B) return;
  u16* xh = (u16*)ws;
  float* covp = (float*)(ws + XH_B);
  float* Sp = (float*)(ws + XH_B + CP_B);
  u16* wtb = (u16*)(ws + XH_B + CP_B + SP_B);
  u16* vb  = (u16*)(ws + XH_B + CP_B + SP_B + WT_B);

  k1_transpose<<<dim3(512, 4), 256, 0, stream>>>(x, xh);
  k2_cov<<<dim3(4, 256), 256, 0, stream>>>(xh, covp, Sp);
  k3_chol<<<dim3(256), 256, 0, stream>>>(covp, Sp, wtb, vb);
  k45_solve<<<dim3(256, 8), 256, 0, stream>>>(xh, wtb, vb, out);
}

// Round 11
// 357.488 us; speedup vs baseline: 1.1492x; 1.0116x over previous
//
#include <hip/hip_runtime.h>
#include <math.h>

#define Bn 4096
#define Dn 64
#define Kn 256
#define DKn 16384
#define SLAB ((size_t)262144)   // per-k slab in xh: Bn*Dn

typedef __attribute__((ext_vector_type(8))) short bf16x8;
typedef __attribute__((ext_vector_type(4))) float f32x4;
typedef unsigned short u16;
typedef unsigned int u32;

__device__ __forceinline__ float bf2f(u16 u) {
  return __uint_as_float(((u32)u) << 16);
}
__device__ __forceinline__ u16 f2bf(float f) {  // RNE
  u32 x = __float_as_uint(f);
  u32 r = x + 0x7fffu + ((x >> 16) & 1u);
  return (u16)(r >> 16);
}
// wave-internal LDS ordering fence: DS ops of one wave are FIFO; this stops
// compiler reordering (rule #18) at zero runtime cost.
__device__ __forceinline__ void wave_lds_fence() {
  asm volatile("s_waitcnt lgkmcnt(0)" ::: "memory");
  __builtin_amdgcn_sched_barrier(0);
}

// ---- K1: x[B,D,K] fp32 -> xh[k][b][d] bf16; double-buffered, 1 barrier/iter
__global__ __launch_bounds__(256) void k1_transpose(
    const float* __restrict__ x, u16* __restrict__ xh) {
  __shared__ float tf[2][64][65];
  const int b0 = blockIdx.x * 8;
  const int k0 = blockIdx.y * 64;
  const int t = threadIdx.x;
  const int kq = t & 15, dsub = t >> 4;
  const int dq = t & 7, kr = t >> 3;

  float4 rv[4];
#pragma unroll
  for (int i = 0; i < 4; ++i)
    rv[i] = *(const float4*)&x[(size_t)b0 * DKn + (size_t)(dsub + 16 * i) * Kn + k0 + 4 * kq];
#pragma unroll
  for (int i = 0; i < 4; ++i) {
    const int d = dsub + 16 * i;
    tf[0][4 * kq + 0][d] = rv[i].x;
    tf[0][4 * kq + 1][d] = rv[i].y;
    tf[0][4 * kq + 2][d] = rv[i].z;
    tf[0][4 * kq + 3][d] = rv[i].w;
  }
  __syncthreads();

  for (int bb = 0; bb < 8; ++bb) {
    const int cur = bb & 1;
    if (bb < 7) {  // issue next-b loads early; latency hides under write-out
#pragma unroll
      for (int i = 0; i < 4; ++i)
        rv[i] = *(const float4*)&x[(size_t)(b0 + bb + 1) * DKn +
                                   (size_t)(dsub + 16 * i) * Kn + k0 + 4 * kq];
    }
#pragma unroll
    for (int it = 0; it < 2; ++it) {
      const int k = kr + 32 * it;
      u32 pk[4];
#pragma unroll
      for (int j = 0; j < 4; ++j) {
        const float f0 = tf[cur][k][8 * dq + 2 * j];
        const float f1 = tf[cur][k][8 * dq + 2 * j + 1];
        pk[j] = (u32)f2bf(f0) | ((u32)f2bf(f1) << 16);
      }
      *(uint4*)&xh[(size_t)(k0 + k) * SLAB + (size_t)(b0 + bb) * 64 + 8 * dq] =
          make_uint4(pk[0], pk[1], pk[2], pk[3]);
    }
    if (bb < 7) {
#pragma unroll
      for (int i = 0; i < 4; ++i) {
        const int d = dsub + 16 * i;
        tf[cur ^ 1][4 * kq + 0][d] = rv[i].x;
        tf[cur ^ 1][4 * kq + 1][d] = rv[i].y;
        tf[cur ^ 1][4 * kq + 2][d] = rv[i].z;
        tf[cur ^ 1][4 * kq + 3][d] = rv[i].w;
      }
      __syncthreads();
    }
  }
}

// ---- K2: cov partials via MFMA; double-buffered tile, 1 barrier/sub --------
union __align__(16) K2SMem {
  u16 tile[2][64][136];   // [buf][d][b], u32-col swizzled by 4*((d>>2)&7) (34816 B)
  float sred[64][33];     // overlaid after last MFMA (8448 B)
};

__global__ __launch_bounds__(256) void k2_cov(
    const u16* __restrict__ xh, float* __restrict__ covp, float* __restrict__ Sp) {
  __shared__ K2SMem s2;
  const int part = blockIdx.x;
  const int k = blockIdx.y;
  const int t = threadIdx.x;
  const int w = t >> 6, l = t & 63;
  const int r16 = l & 15, g = l >> 4;
  const int q = t >> 3, c = t & 7;  // q 0..31 (4-row group), c 0..7 (d-chunk)
  const u16* pk = xh + (size_t)k * SLAB;

  f32x4 hh[10];
#pragma unroll
  for (int p = 0; p < 10; ++p) hh[p] = (f32x4){0.f, 0.f, 0.f, 0.f};
  float dsums[8];
#pragma unroll
  for (int jj = 0; jj < 8; ++jj) dsums[jj] = 0.f;

  uint4 pv[4];
#define K2_LOAD(SUB)                                                           \
  {                                                                            \
    const int bbase = part * 1024 + (SUB) * 128;                               \
    _Pragma("unroll") for (int i = 0; i < 4; ++i)                              \
        pv[i] = *(const uint4*)&pk[(size_t)(bbase + 4 * q + i) * 64 + c * 8];  \
  }
#define K2_STORE(BUF)                                                          \
  {                                                                            \
    const u16* e0 = (const u16*)&pv[0];                                        \
    const u16* e1 = (const u16*)&pv[1];                                        \
    const u16* e2 = (const u16*)&pv[2];                                        \
    const u16* e3 = (const u16*)&pv[3];                                        \
    _Pragma("unroll") for (int jj = 0; jj < 8; ++jj) {                         \
      const int d = 8 * c + jj;                                                \
      const int s4 = 4 * ((d >> 2) & 7);                                       \
      const u16 v0 = e0[jj], v1 = e1[jj], v2 = e2[jj], v3 = e3[jj];            \
      dsums[jj] += (bf2f(v0) + bf2f(v1)) + (bf2f(v2) + bf2f(v3));              \
      const int col0 = (2 * q) ^ s4;                                           \
      uint2 st;                                                                \
      st.x = (u32)v0 | ((u32)v1 << 16);                                        \
      st.y = (u32)v2 | ((u32)v3 << 16);                                        \
      *(uint2*)&s2.tile[BUF][d][2 * col0] = st;                                \
    }                                                                          \
  }

  K2_LOAD(0);
  K2_STORE(0);
  __syncthreads();
  for (int sub = 0; sub < 8; ++sub) {
    const int cur = sub & 1;
    if (sub < 7) K2_LOAD(sub + 1);  // issue early; hides under MFMA
    bf16x8 fr[4];
#pragma unroll
    for (int m = 0; m < 4; ++m) {
      const int d = 16 * m + r16;
      const int s4 = 4 * ((d >> 2) & 7);
      const int colb = (16 * w + 4 * g) ^ s4;
      fr[m] = *(const bf16x8*)&s2.tile[cur][d][2 * colb];
    }
#pragma unroll
    for (int m = 0; m < 4; ++m)
#pragma unroll
      for (int n = m; n < 4; ++n) {
        const int p = (m * (7 - m)) / 2 + n;
        hh[p] = __builtin_amdgcn_mfma_f32_16x16x32_bf16(fr[m], fr[n], hh[p], 0, 0, 0);
      }
    if (sub < 7) {
      K2_STORE(cur ^ 1);
      __syncthreads();
    }
  }
  float* cp = covp + ((size_t)k * 16 + part * 4 + w) * 2560;
#pragma unroll
  for (int p = 0; p < 10; ++p)
#pragma unroll
    for (int r = 0; r < 4; ++r)
      cp[p * 256 + (g * 4 + r) * 16 + r16] = hh[p][r];
  __syncthreads();  // all MFMA reads done before sred overlays tile
#pragma unroll
  for (int jj = 0; jj < 8; ++jj) s2.sred[8 * c + jj][q] = dsums[jj];
  __syncthreads();
  if (t < 64) {
    float s = 0.f;
#pragma unroll
    for (int q2 = 0; q2 < 32; ++q2) s += s2.sred[t][q2];
    Sp[((size_t)k * 4 + part) * 64 + t] = s;
  }
}

// ---- K3: reduce -> cov -> wave-synchronous Cholesky -> Linv + v ------------
__global__ __launch_bounds__(256) void k3_chol(
    const float* __restrict__ covp, const float* __restrict__ Sp,
    u16* __restrict__ wt, u16* __restrict__ vout) {
  __shared__ float a[64][65];
  __shared__ float mus[64];
  __shared__ float colv[64];
  const int k = blockIdx.x;
  const int tid = threadIdx.x;
  if (tid < 64) {
    float s = 0.f;
#pragma unroll
    for (int q = 0; q < 4; ++q) s += Sp[((size_t)k * 4 + q) * 64 + tid];
    mus[tid] = s * (1.f / 4096.f);
  }
  __syncthreads();
  const float* cp = covp + (size_t)k * 16 * 2560;
  for (int idx = tid; idx < 4096; idx += 256) {
    const int i = idx >> 6, j = idx & 63;
    const int i16 = i >> 4, j16 = j >> 4, r = i & 15, c = j & 15;
    int p, off;
    if (i16 <= j16) { p = (i16 * (7 - i16)) / 2 + j16; off = r * 16 + c; }
    else            { p = (j16 * (7 - j16)) / 2 + i16; off = c * 16 + r; }
    float s = 0.f;
#pragma unroll
    for (int q = 0; q < 16; ++q) s += cp[q * 2560 + p * 256 + off];
    float cv = (s - 4096.f * mus[i] * mus[j]) * (1.f / 4095.f);
    if (i == j) cv += 1e-4f;
    a[i][j] = cv;
  }
  __syncthreads();

  // Phase B: wave 0 only; lockstep wave => no block barriers needed.
  if (tid < 64) {
    for (int j = 0; j < 64; ++j) {
      wave_lds_fence();
      const float ljj = sqrtf(a[j][j]);  // broadcast LDS read, all lanes
      float lij = 0.f;
      if (tid == j) a[j][j] = ljj;
      if (tid > j) {
        lij = a[tid][j] / ljj;
        a[tid][j] = lij;
        colv[tid] = lij;
      }
      wave_lds_fence();
      if (tid > j) {
        for (int e = j + 1; e <= tid; ++e) a[tid][e] -= lij * colv[e];
      }
    }
    wave_lds_fence();
    // inversion: lane solves L w = e_lane (fully unrolled, registers)
    float wv[64];
#pragma unroll
    for (int i = 0; i < 64; ++i) {
      float s2 = (i == tid) ? 1.f : 0.f;
#pragma unroll
      for (int j = 0; j < i; ++j) s2 -= a[i][j] * wv[j];
      wv[i] = (i >= tid) ? s2 / a[i][i] : 0.f;
    }
    wave_lds_fence();  // all L reads issued before overwrite (lockstep wave)
#pragma unroll
    for (int i = 0; i < 64; ++i) a[i][tid] = wv[i];  // a = Linv row-major
    wave_lds_fence();
    float v = 0.f;
#pragma unroll
    for (int e = 0; e < 64; ++e) v += a[tid][e] * mus[e];
    vout[(size_t)k * 64 + tid] = f2bf(v);
  }
  __syncthreads();
#pragma unroll
  for (int it = 0; it < 8; ++it) {
    const int idx = it * 256 + tid;
    const int dd = idx >> 5, ep = idx & 31;
    const u32 pk2 = (u32)f2bf(a[dd][2 * ep]) | ((u32)f2bf(a[dd][2 * ep + 1]) << 16);
    *(u32*)&wt[(size_t)k * 4096 + 2 * idx] = pk2;
  }
}

// ---- K45 (R10 version, unchanged): LDS-staged B, cvt_pk, k-major zls out ---
union __align__(16) SMemU {
  u16 xstage[2][8][16][64];  // [buf][k][b][d], d-chunk XOR-swizzled by b&7 (32768 B)
  u32 zls[16 * 642 + 40];    // 41248 B
};

__global__ __launch_bounds__(256) void k45_solve(
    const u16* __restrict__ xh, const u16* __restrict__ wt,
    const u16* __restrict__ vin, float* __restrict__ out) {
  __shared__ SMemU sm;
  __shared__ __align__(16) u16 vsh[32][72];  // [k][d]
  const int b0 = blockIdx.x * 16;
  const int kc0 = blockIdx.y * 32;
  const int t = threadIdx.x;
  const int w = t >> 6, l = t & 63;
  const int r16 = l & 15, g = l >> 4;
  const int d0 = 16 * w + 4 * g;

  *(uint4*)&vsh[t >> 3][8 * (t & 7)] = *(const uint4*)&vin[(size_t)kc0 * 64 + t * 8];

  uint4 sv[4];
#pragma unroll
  for (int i = 0; i < 4; ++i) {
    const int idx = i * 256 + t;
    const int kk = idx >> 7, b = (idx >> 3) & 15, dc = idx & 7;
    sv[i] = *(const uint4*)&xh[(size_t)(kc0 + kk) * SLAB + (size_t)(b0 + b) * 64 + dc * 8];
  }
#pragma unroll
  for (int i = 0; i < 4; ++i) {
    const int idx = i * 256 + t;
    const int kk = idx >> 7, b = (idx >> 3) & 15, dc = idx & 7;
    *(uint4*)&sm.xstage[0][kk][b][(dc ^ (b & 7)) * 8] = sv[i];
  }

  bf16x8 af0[4], af1[4];
#pragma unroll
  for (int p = 0; p < 4; ++p) {
    const u16* wk = wt + (size_t)(kc0 + p) * 4096 + (16 * w + r16) * 64 + 8 * g;
    af0[p] = *(const bf16x8*)(wk);
    af1[p] = *(const bf16x8*)(wk + 32);
  }
  __syncthreads();

  u32 zr[64];

#pragma unroll
  for (int rnd = 0; rnd < 4; ++rnd) {
    if (rnd < 3) {
#pragma unroll
      for (int i = 0; i < 4; ++i) {
        const int idx = i * 256 + t;
        const int kk = idx >> 7, b = (idx >> 3) & 15, dc = idx & 7;
        sv[i] = *(const uint4*)&xh[(size_t)(kc0 + (rnd + 1) * 8 + kk) * SLAB +
                                   (size_t)(b0 + b) * 64 + dc * 8];
      }
    }
#pragma unroll
    for (int kk = 0; kk < 8; ++kk) {
      const int kidx = rnd * 8 + kk;
      const bf16x8 a0 = af0[kidx & 3];
      const bf16x8 a1 = af1[kidx & 3];
      if (kidx + 4 < 32) {
        const u16* wk = wt + (size_t)(kc0 + kidx + 4) * 4096 + (16 * w + r16) * 64 + 8 * g;
        af0[kidx & 3] = *(const bf16x8*)(wk);
        af1[kidx & 3] = *(const bf16x8*)(wk + 32);
      }
      const bf16x8 bf0 = *(const bf16x8*)&sm.xstage[rnd & 1][kk][r16][(g ^ (r16 & 7)) * 8];
      const bf16x8 bf1 = *(const bf16x8*)&sm.xstage[rnd & 1][kk][r16][((4 + g) ^ (r16 & 7)) * 8];
      f32x4 acc = (f32x4){0.f, 0.f, 0.f, 0.f};
      acc = __builtin_amdgcn_mfma_f32_16x16x32_bf16(a0, bf0, acc, 0, 0, 0);
      acc = __builtin_amdgcn_mfma_f32_16x16x32_bf16(a1, bf1, acc, 0, 0, 0);
      const uint2 vv = *(const uint2*)&vsh[kidx][d0];
      const float s0 = acc[0] - __uint_as_float(vv.x << 16);
      const float s1 = acc[1] - __uint_as_float(vv.x & 0xffff0000u);
      const float s2 = acc[2] - __uint_as_float(vv.y << 16);
      const float s3 = acc[3] - __uint_as_float(vv.y & 0xffff0000u);
      u32 plo, phi;
      asm("v_cvt_pk_bf16_f32 %0, %1, %2" : "=v"(plo) : "v"(s0), "v"(s1));
      asm("v_cvt_pk_bf16_f32 %0, %1, %2" : "=v"(phi) : "v"(s2), "v"(s3));
      zr[2 * kidx] = plo;
      zr[2 * kidx + 1] = phi;
    }
    if (rnd < 3) {
#pragma unroll
      for (int i = 0; i < 4; ++i) {
        const int idx = i * 256 + t;
        const int kk = idx >> 7, b = (idx >> 3) & 15, dc = idx & 7;
        *(uint4*)&sm.xstage[(rnd + 1) & 1][kk][b][(dc ^ (b & 7)) * 8] = sv[i];
      }
      __syncthreads();
    }
  }
  __syncthreads();

#pragma unroll
  for (int h = 0; h < 2; ++h) {
    u32 W[4][8];
#pragma unroll
    for (int r = 0; r < 4; ++r)
#pragma unroll
      for (int q2 = 0; q2 < 8; ++q2) {
        const int k2 = 16 * h + 2 * q2;
        const u32 za = zr[2 * k2 + (r >> 1)];
        const u32 zb2 = zr[2 * (k2 + 1) + (r >> 1)];
        W[r][q2] = (r & 1) ? ((za >> 16) | (zb2 & 0xffff0000u))
                           : ((za & 0xffffu) | (zb2 << 16));
      }
#pragma unroll
    for (int r = 0; r < 4; ++r) {
      u32* cp = &sm.zls[r16 * 642 + (d0 + r) * 10];
      *(uint2*)&cp[0] = make_uint2(W[r][0], W[r][1]);
      *(uint2*)&cp[2] = make_uint2(W[r][2], W[r][3]);
      *(uint2*)&cp[4] = make_uint2(W[r][4], W[r][5]);
      *(uint2*)&cp[6] = make_uint2(W[r][6], W[r][7]);
    }
    __syncthreads();
#pragma unroll
    for (int it = 0; it < 16; ++it) {
      const int c = w * 256 + it * 16 + (l >> 2);
      const int kc = l & 3;
      const int b = c >> 6, d = c & 63;
      const uint2 zw = *(const uint2*)&sm.zls[b * 642 + d * 10 + 2 * kc];
      float4 ov;
      ov.x = __uint_as_float(zw.x << 16);
      ov.y = __uint_as_float(zw.x & 0xffff0000u);
      ov.z = __uint_as_float(zw.y << 16);
      ov.w = __uint_as_float(zw.y & 0xffff0000u);
      *(float4*)&out[(size_t)(b0 + b) * DKn + (size_t)d * Kn + kc0 + 16 * h + 4 * kc] = ov;
    }
    __syncthreads();
  }
}

extern "C" void kernel_launch(void* const* d_in, const int* in_sizes, int n_in,
                              void* d_out, int out_size, void* d_ws, size_t ws_size,
                              hipStream_t stream) {
  (void)in_sizes; (void)n_in; (void)out_size;
  const float* x = (const float*)d_in[0];
  float* out = (float*)d_out;
  char* ws = (char*)d_ws;
  const size_t XH_B = 134217728;   // u16 [256][4096][64]
  const size_t CP_B = 41943040;    // f32 [256][16][2560]
  const size_t SP_B = 262144;      // f32 [256][4][64]
  const size_t WT_B = 2097152;     // u16 [256][64][64]
  const size_t V_B  = 32768;       // u16 [256][64]
  if (ws_size < XH_B + CP_B + SP_B + WT_B + V_B) return;
  u16* xh = (u16*)ws;
  float* covp = (float*)(ws + XH_B);
  float* Sp = (float*)(ws + XH_B + CP_B);
  u16* wtb = (u16*)(ws + XH_B + CP_B + SP_B);
  u16* vb  = (u16*)(ws + XH_B + CP_B + SP_B + WT_B);

  k1_transpose<<<dim3(512, 4), 256, 0, stream>>>(x, xh);
  k2_cov<<<dim3(4, 256), 256, 0, stream>>>(xh, covp, Sp);
  k3_chol<<<dim3(256), 256, 0, stream>>>(covp, Sp, wtb, vb);
  k45_solve<<<dim3(256, 8), 256, 0, stream>>>(xh, wtb, vb, out);
}

// Round 12
// 354.443 us; speedup vs baseline: 1.1591x; 1.0086x over previous
//
#include <hip/hip_runtime.h>
#include <math.h>

#define Bn 4096
#define Dn 64
#define Kn 256
#define DKn 16384
#define SLAB ((size_t)262144)   // per-k slab in xh: Bn*Dn

typedef __attribute__((ext_vector_type(8))) short bf16x8;
typedef __attribute__((ext_vector_type(4))) float f32x4;
typedef unsigned short u16;
typedef unsigned int u32;

__device__ __forceinline__ float bf2f(u16 u) {
  return __uint_as_float(((u32)u) << 16);
}
__device__ __forceinline__ u16 f2bf(float f) {  // RNE
  u32 x = __float_as_uint(f);
  u32 r = x + 0x7fffu + ((x >> 16) & 1u);
  return (u16)(r >> 16);
}
// wave-internal LDS ordering fence (rule #18): stops compiler reordering.
__device__ __forceinline__ void wave_lds_fence() {
  asm volatile("s_waitcnt lgkmcnt(0)" ::: "memory");
  __builtin_amdgcn_sched_barrier(0);
}

// ---- K1: x[B,D,K] fp32 -> xh[k][b][d] bf16; double-buffered, 1 barrier/iter
__global__ __launch_bounds__(256) void k1_transpose(
    const float* __restrict__ x, u16* __restrict__ xh) {
  __shared__ float tf[2][64][65];
  const int b0 = blockIdx.x * 8;
  const int k0 = blockIdx.y * 64;
  const int t = threadIdx.x;
  const int kq = t & 15, dsub = t >> 4;
  const int dq = t & 7, kr = t >> 3;

  float4 rv[4];
#pragma unroll
  for (int i = 0; i < 4; ++i)
    rv[i] = *(const float4*)&x[(size_t)b0 * DKn + (size_t)(dsub + 16 * i) * Kn + k0 + 4 * kq];
#pragma unroll
  for (int i = 0; i < 4; ++i) {
    const int d = dsub + 16 * i;
    tf[0][4 * kq + 0][d] = rv[i].x;
    tf[0][4 * kq + 1][d] = rv[i].y;
    tf[0][4 * kq + 2][d] = rv[i].z;
    tf[0][4 * kq + 3][d] = rv[i].w;
  }
  __syncthreads();

  for (int bb = 0; bb < 8; ++bb) {
    const int cur = bb & 1;
    if (bb < 7) {
#pragma unroll
      for (int i = 0; i < 4; ++i)
        rv[i] = *(const float4*)&x[(size_t)(b0 + bb + 1) * DKn +
                                   (size_t)(dsub + 16 * i) * Kn + k0 + 4 * kq];
    }
#pragma unroll
    for (int it = 0; it < 2; ++it) {
      const int k = kr + 32 * it;
      u32 pk[4];
#pragma unroll
      for (int j = 0; j < 4; ++j) {
        const float f0 = tf[cur][k][8 * dq + 2 * j];
        const float f1 = tf[cur][k][8 * dq + 2 * j + 1];
        pk[j] = (u32)f2bf(f0) | ((u32)f2bf(f1) << 16);
      }
      *(uint4*)&xh[(size_t)(k0 + k) * SLAB + (size_t)(b0 + bb) * 64 + 8 * dq] =
          make_uint4(pk[0], pk[1], pk[2], pk[3]);
    }
    if (bb < 7) {
#pragma unroll
      for (int i = 0; i < 4; ++i) {
        const int d = dsub + 16 * i;
        tf[cur ^ 1][4 * kq + 0][d] = rv[i].x;
        tf[cur ^ 1][4 * kq + 1][d] = rv[i].y;
        tf[cur ^ 1][4 * kq + 2][d] = rv[i].z;
        tf[cur ^ 1][4 * kq + 3][d] = rv[i].w;
      }
      __syncthreads();
    }
  }
}

// ---- K2: cov partials via MFMA; double-buffered tile, 1 barrier/sub --------
union __align__(16) K2SMem {
  u16 tile[2][64][136];   // [buf][d][b], u32-col swizzled by 4*((d>>2)&7)
  float sred[64][33];
};

__global__ __launch_bounds__(256) void k2_cov(
    const u16* __restrict__ xh, float* __restrict__ covp, float* __restrict__ Sp) {
  __shared__ K2SMem s2;
  const int part = blockIdx.x;
  const int k = blockIdx.y;
  const int t = threadIdx.x;
  const int w = t >> 6, l = t & 63;
  const int r16 = l & 15, g = l >> 4;
  const int q = t >> 3, c = t & 7;
  const u16* pk = xh + (size_t)k * SLAB;

  f32x4 hh[10];
#pragma unroll
  for (int p = 0; p < 10; ++p) hh[p] = (f32x4){0.f, 0.f, 0.f, 0.f};
  float dsums[8];
#pragma unroll
  for (int jj = 0; jj < 8; ++jj) dsums[jj] = 0.f;

  uint4 pv[4];
#define K2_LOAD(SUB)                                                           \
  {                                                                            \
    const int bbase = part * 1024 + (SUB) * 128;                               \
    _Pragma("unroll") for (int i = 0; i < 4; ++i)                              \
        pv[i] = *(const uint4*)&pk[(size_t)(bbase + 4 * q + i) * 64 + c * 8];  \
  }
#define K2_STORE(BUF)                                                          \
  {                                                                            \
    const u16* e0 = (const u16*)&pv[0];                                        \
    const u16* e1 = (const u16*)&pv[1];                                        \
    const u16* e2 = (const u16*)&pv[2];                                        \
    const u16* e3 = (const u16*)&pv[3];                                        \
    _Pragma("unroll") for (int jj = 0; jj < 8; ++jj) {                         \
      const int d = 8 * c + jj;                                                \
      const int s4 = 4 * ((d >> 2) & 7);                                       \
      const u16 v0 = e0[jj], v1 = e1[jj], v2 = e2[jj], v3 = e3[jj];            \
      dsums[jj] += (bf2f(v0) + bf2f(v1)) + (bf2f(v2) + bf2f(v3));              \
      const int col0 = (2 * q) ^ s4;                                           \
      uint2 st;                                                                \
      st.x = (u32)v0 | ((u32)v1 << 16);                                        \
      st.y = (u32)v2 | ((u32)v3 << 16);                                        \
      *(uint2*)&s2.tile[BUF][d][2 * col0] = st;                                \
    }                                                                          \
  }

  K2_LOAD(0);
  K2_STORE(0);
  __syncthreads();
  for (int sub = 0; sub < 8; ++sub) {
    const int cur = sub & 1;
    if (sub < 7) K2_LOAD(sub + 1);
    bf16x8 fr[4];
#pragma unroll
    for (int m = 0; m < 4; ++m) {
      const int d = 16 * m + r16;
      const int s4 = 4 * ((d >> 2) & 7);
      const int colb = (16 * w + 4 * g) ^ s4;
      fr[m] = *(const bf16x8*)&s2.tile[cur][d][2 * colb];
    }
#pragma unroll
    for (int m = 0; m < 4; ++m)
#pragma unroll
      for (int n = m; n < 4; ++n) {
        const int p = (m * (7 - m)) / 2 + n;
        hh[p] = __builtin_amdgcn_mfma_f32_16x16x32_bf16(fr[m], fr[n], hh[p], 0, 0, 0);
      }
    if (sub < 7) {
      K2_STORE(cur ^ 1);
      __syncthreads();
    }
  }
  float* cp = covp + ((size_t)k * 16 + part * 4 + w) * 2560;
#pragma unroll
  for (int p = 0; p < 10; ++p)
#pragma unroll
    for (int r = 0; r < 4; ++r)
      cp[p * 256 + (g * 4 + r) * 16 + r16] = hh[p][r];
  __syncthreads();
#pragma unroll
  for (int jj = 0; jj < 8; ++jj) s2.sred[8 * c + jj][q] = dsums[jj];
  __syncthreads();
  if (t < 64) {
    float s = 0.f;
#pragma unroll
    for (int q2 = 0; q2 < 32; ++q2) s += s2.sred[t][q2];
    Sp[((size_t)k * 4 + part) * 64 + t] = s;
  }
}

// ---- K3: reduce -> cov -> wave-synchronous Cholesky -> Linv + v ------------
__global__ __launch_bounds__(256) void k3_chol(
    const float* __restrict__ covp, const float* __restrict__ Sp,
    u16* __restrict__ wt, u16* __restrict__ vout) {
  __shared__ float a[64][65];
  __shared__ float mus[64];
  __shared__ float colv[64];
  const int k = blockIdx.x;
  const int tid = threadIdx.x;
  if (tid < 64) {
    float s = 0.f;
#pragma unroll
    for (int q = 0; q < 4; ++q) s += Sp[((size_t)k * 4 + q) * 64 + tid];
    mus[tid] = s * (1.f / 4096.f);
  }
  __syncthreads();
  const float* cp = covp + (size_t)k * 16 * 2560;
  for (int idx = tid; idx < 4096; idx += 256) {
    const int i = idx >> 6, j = idx & 63;
    const int i16 = i >> 4, j16 = j >> 4, r = i & 15, c = j & 15;
    int p, off;
    if (i16 <= j16) { p = (i16 * (7 - i16)) / 2 + j16; off = r * 16 + c; }
    else            { p = (j16 * (7 - j16)) / 2 + i16; off = c * 16 + r; }
    float s = 0.f;
#pragma unroll
    for (int q = 0; q < 16; ++q) s += cp[q * 2560 + p * 256 + off];
    float cv = (s - 4096.f * mus[i] * mus[j]) * (1.f / 4095.f);
    if (i == j) cv += 1e-4f;
    a[i][j] = cv;
  }
  __syncthreads();

  if (tid < 64) {
    for (int j = 0; j < 64; ++j) {
      wave_lds_fence();
      const float ljj = sqrtf(a[j][j]);
      float lij = 0.f;
      if (tid == j) a[j][j] = ljj;
      if (tid > j) {
        lij = a[tid][j] / ljj;
        a[tid][j] = lij;
        colv[tid] = lij;
      }
      wave_lds_fence();
      if (tid > j) {
        for (int e = j + 1; e <= tid; ++e) a[tid][e] -= lij * colv[e];
      }
    }
    wave_lds_fence();
    float wv[64];
#pragma unroll
    for (int i = 0; i < 64; ++i) {
      float s2 = (i == tid) ? 1.f : 0.f;
#pragma unroll
      for (int j = 0; j < i; ++j) s2 -= a[i][j] * wv[j];
      wv[i] = (i >= tid) ? s2 / a[i][i] : 0.f;
    }
    wave_lds_fence();
#pragma unroll
    for (int i = 0; i < 64; ++i) a[i][tid] = wv[i];  // a = Linv row-major
    wave_lds_fence();
    float v = 0.f;
#pragma unroll
    for (int e = 0; e < 64; ++e) v += a[tid][e] * mus[e];
    vout[(size_t)k * 64 + tid] = f2bf(v);
  }
  __syncthreads();
#pragma unroll
  for (int it = 0; it < 8; ++it) {
    const int idx = it * 256 + tid;
    const int dd = idx >> 5, ep = idx & 31;
    const u32 pk2 = (u32)f2bf(a[dd][2 * ep]) | ((u32)f2bf(a[dd][2 * ep + 1]) << 16);
    *(u32*)&wt[(size_t)k * 4096 + 2 * idx] = pk2;
  }
}

// ---- K45: grid SWAPPED (x = k-chunk fastest) for DRAM write-row locality ---
// grid (8 k-chunks of 32, 256 b-tiles of 16), block 256 (4 waves = d-quarters)
union __align__(16) SMemU {
  u16 xstage[2][8][16][64];  // [buf][k][b][d], d-chunk XOR-swizzled by b&7
  u32 zls[16 * 642 + 40];    // 41248 B
};

__global__ __launch_bounds__(256) void k45_solve(
    const u16* __restrict__ xh, const u16* __restrict__ wt,
    const u16* __restrict__ vin, float* __restrict__ out) {
  __shared__ SMemU sm;
  __shared__ __align__(16) u16 vsh[32][72];  // [k][d]
  const int kc0 = blockIdx.x * 32;   // SWAPPED: k-chunk varies fastest
  const int b0 = blockIdx.y * 16;
  const int t = threadIdx.x;
  const int w = t >> 6, l = t & 63;
  const int r16 = l & 15, g = l >> 4;
  const int d0 = 16 * w + 4 * g;

  *(uint4*)&vsh[t >> 3][8 * (t & 7)] = *(const uint4*)&vin[(size_t)kc0 * 64 + t * 8];

  uint4 sv[4];
#pragma unroll
  for (int i = 0; i < 4; ++i) {
    const int idx = i * 256 + t;
    const int kk = idx >> 7, b = (idx >> 3) & 15, dc = idx & 7;
    sv[i] = *(const uint4*)&xh[(size_t)(kc0 + kk) * SLAB + (size_t)(b0 + b) * 64 + dc * 8];
  }
#pragma unroll
  for (int i = 0; i < 4; ++i) {
    const int idx = i * 256 + t;
    const int kk = idx >> 7, b = (idx >> 3) & 15, dc = idx & 7;
    *(uint4*)&sm.xstage[0][kk][b][(dc ^ (b & 7)) * 8] = sv[i];
  }

  bf16x8 af0[4], af1[4];
#pragma unroll
  for (int p = 0; p < 4; ++p) {
    const u16* wk = wt + (size_t)(kc0 + p) * 4096 + (16 * w + r16) * 64 + 8 * g;
    af0[p] = *(const bf16x8*)(wk);
    af1[p] = *(const bf16x8*)(wk + 32);
  }
  __syncthreads();

  u32 zr[64];

#pragma unroll
  for (int rnd = 0; rnd < 4; ++rnd) {
    if (rnd < 3) {
#pragma unroll
      for (int i = 0; i < 4; ++i) {
        const int idx = i * 256 + t;
        const int kk = idx >> 7, b = (idx >> 3) & 15, dc = idx & 7;
        sv[i] = *(const uint4*)&xh[(size_t)(kc0 + (rnd + 1) * 8 + kk) * SLAB +
                                   (size_t)(b0 + b) * 64 + dc * 8];
      }
    }
#pragma unroll
    for (int kk = 0; kk < 8; ++kk) {
      const int kidx = rnd * 8 + kk;
      const bf16x8 a0 = af0[kidx & 3];
      const bf16x8 a1 = af1[kidx & 3];
      if (kidx + 4 < 32) {
        const u16* wk = wt + (size_t)(kc0 + kidx + 4) * 4096 + (16 * w + r16) * 64 + 8 * g;
        af0[kidx & 3] = *(const bf16x8*)(wk);
        af1[kidx & 3] = *(const bf16x8*)(wk + 32);
      }
      const bf16x8 bf0 = *(const bf16x8*)&sm.xstage[rnd & 1][kk][r16][(g ^ (r16 & 7)) * 8];
      const bf16x8 bf1 = *(const bf16x8*)&sm.xstage[rnd & 1][kk][r16][((4 + g) ^ (r16 & 7)) * 8];
      f32x4 acc = (f32x4){0.f, 0.f, 0.f, 0.f};
      acc = __builtin_amdgcn_mfma_f32_16x16x32_bf16(a0, bf0, acc, 0, 0, 0);
      acc = __builtin_amdgcn_mfma_f32_16x16x32_bf16(a1, bf1, acc, 0, 0, 0);
      const uint2 vv = *(const uint2*)&vsh[kidx][d0];
      const float s0 = acc[0] - __uint_as_float(vv.x << 16);
      const float s1 = acc[1] - __uint_as_float(vv.x & 0xffff0000u);
      const float s2 = acc[2] - __uint_as_float(vv.y << 16);
      const float s3 = acc[3] - __uint_as_float(vv.y & 0xffff0000u);
      u32 plo, phi;
      asm("v_cvt_pk_bf16_f32 %0, %1, %2" : "=v"(plo) : "v"(s0), "v"(s1));
      asm("v_cvt_pk_bf16_f32 %0, %1, %2" : "=v"(phi) : "v"(s2), "v"(s3));
      zr[2 * kidx] = plo;
      zr[2 * kidx + 1] = phi;
    }
    if (rnd < 3) {
#pragma unroll
      for (int i = 0; i < 4; ++i) {
        const int idx = i * 256 + t;
        const int kk = idx >> 7, b = (idx >> 3) & 15, dc = idx & 7;
        *(uint4*)&sm.xstage[(rnd + 1) & 1][kk][b][(dc ^ (b & 7)) * 8] = sv[i];
      }
      __syncthreads();
    }
  }
  __syncthreads();

#pragma unroll
  for (int h = 0; h < 2; ++h) {
    u32 W[4][8];
#pragma unroll
    for (int r = 0; r < 4; ++r)
#pragma unroll
      for (int q2 = 0; q2 < 8; ++q2) {
        const int k2 = 16 * h + 2 * q2;
        const u32 za = zr[2 * k2 + (r >> 1)];
        const u32 zb2 = zr[2 * (k2 + 1) + (r >> 1)];
        W[r][q2] = (r & 1) ? ((za >> 16) | (zb2 & 0xffff0000u))
                           : ((za & 0xffffu) | (zb2 << 16));
      }
#pragma unroll
    for (int r = 0; r < 4; ++r) {
      u32* cp = &sm.zls[r16 * 642 + (d0 + r) * 10];
      *(uint2*)&cp[0] = make_uint2(W[r][0], W[r][1]);
      *(uint2*)&cp[2] = make_uint2(W[r][2], W[r][3]);
      *(uint2*)&cp[4] = make_uint2(W[r][4], W[r][5]);
      *(uint2*)&cp[6] = make_uint2(W[r][6], W[r][7]);
    }
    __syncthreads();
#pragma unroll
    for (int it = 0; it < 16; ++it) {
      const int c = w * 256 + it * 16 + (l >> 2);
      const int kc = l & 3;
      const int b = c >> 6, d = c & 63;
      const uint2 zw = *(const uint2*)&sm.zls[b * 642 + d * 10 + 2 * kc];
      float4 ov;
      ov.x = __uint_as_float(zw.x << 16);
      ov.y = __uint_as_float(zw.x & 0xffff0000u);
      ov.z = __uint_as_float(zw.y << 16);
      ov.w = __uint_as_float(zw.y & 0xffff0000u);
      *(float4*)&out[(size_t)(b0 + b) * DKn + (size_t)d * Kn + kc0 + 16 * h + 4 * kc] = ov;
    }
    __syncthreads();
  }
}

extern "C" void kernel_launch(void* const* d_in, const int* in_sizes, int n_in,
                              void* d_out, int out_size, void* d_ws, size_t ws_size,
                              hipStream_t stream) {
  (void)in_sizes; (void)n_in; (void)out_size;
  const float* x = (const float*)d_in[0];
  float* out = (float*)d_out;
  char* ws = (char*)d_ws;
  const size_t XH_B = 134217728;   // u16 [256][4096][64]
  const size_t CP_B = 41943040;    // f32 [256][16][2560]
  const size_t SP_B = 262144;      // f32 [256][4][64]
  const size_t WT_B = 2097152;     // u16 [256][64][64]
  const size_t V_B  = 32768;       // u16 [256][64]
  if (ws_size < XH_B + CP_B + SP_B + WT_B + V_B) return;
  u16* xh = (u16*)ws;
  float* covp = (float*)(ws + XH_B);
  float* Sp = (float*)(ws + XH_B + CP_B);
  u16* wtb = (u16*)(ws + XH_B + CP_B + SP_B);
  u16* vb  = (u16*)(ws + XH_B + CP_B + SP_B + WT_B);

  k1_transpose<<<dim3(512, 4), 256, 0, stream>>>(x, xh);
  k2_cov<<<dim3(4, 256), 256, 0, stream>>>(xh, covp, Sp);
  k3_chol<<<dim3(256), 256, 0, stream>>>(covp, Sp, wtb, vb);
  k45_solve<<<dim3(8, 256), 256, 0, stream>>>(xh, wtb, vb, out);  // SWAPPED grid
}